// Round 7
// baseline (82387.616 us; speedup 1.0000x reference)
//
#include <hip/hip_runtime.h>
#include <cstdint>

constexpr int B = 32, ET = 1024, DT = 1024, D = 256, PAD = 15, PT = ET + 2*PAD;
constexpr float LOG2E = 1.4426950408889634f;

// ws float layout
constexpr size_t PBUF_OFF = 0;                           // [B][2][PT] prev,cum (halo-padded)
constexpr size_t PART_OFF = PBUF_OFF + (size_t)B*2*PT;   // [B][16][D] att_out partials
constexpr size_t M_OFF    = PART_OFF + (size_t)B*16*D;   // [B][16] tile max
constexpr size_t S_OFF    = M_OFF + (size_t)B*16;        // [B][16] tile exp-sum
constexpr size_t WT2_OFF  = S_OFF + (size_t)B*16;        // [D][64] padded weights: [d][c*32+k]
constexpr size_t CNT_OFF  = WT2_OFF + (size_t)D*64;      // [B] uint barrier counters

__global__ __launch_bounds__(256) void k_init(const float* __restrict__ W,
                                              float* __restrict__ ws) {
  int i0 = blockIdx.x*256 + threadIdx.x;
  int stride = gridDim.x*256;
  for (int i = i0; i < B*2*PT; i += stride) ws[PBUF_OFF + i] = 0.f;
  for (int i = i0; i < B*16*D; i += stride) ws[PART_OFF + i] = 0.f;
  for (int i = i0; i < D*64; i += stride) {       // WT2[d][c*32+k] = W[d][c*31+k], pad k=31 -> 0
    int d = i >> 6, r = i & 63;
    int c = r >> 5, k = r & 31;
    ws[WT2_OFF + i] = (k < 31) ? W[d*62 + c*31 + k] : 0.f;
  }
  if (i0 < B) ((unsigned*)(ws + CNT_OFF))[i0] = 0u;
}

// relaxed agent-scope accessors: coherence-point loads/stores, no cache flushes
__device__ __forceinline__ float aload(const float* p) {
  return __hip_atomic_load(p, __ATOMIC_RELAXED, __HIP_MEMORY_SCOPE_AGENT);
}
__device__ __forceinline__ void astore(float* p, float v) {
  __hip_atomic_store(p, v, __ATOMIC_RELAXED, __HIP_MEMORY_SCOPE_AGENT);
}

// per-batch arrive-and-wait, 16 blocks, monotonic counter, zero fences.
__device__ __forceinline__ void batch_barrier(unsigned* cnt, unsigned target, int tid) {
  __syncthreads();
  if (tid == 0) {
    __hip_atomic_fetch_add(cnt, 1u, __ATOMIC_RELAXED, __HIP_MEMORY_SCOPE_AGENT);
    while (__hip_atomic_load(cnt, __ATOMIC_RELAXED, __HIP_MEMORY_SCOPE_AGENT) < target)
      __builtin_amdgcn_s_sleep(2);
  }
  __syncthreads();
}

__device__ __forceinline__ float read_lane_f(float v, int i) {
  return __int_as_float(__builtin_amdgcn_readlane(__float_as_int(v), i));
}

__global__ __attribute__((amdgpu_flat_work_group_size(256, 256), amdgpu_waves_per_eu(2, 2)))
void k_decoder(
    const float* __restrict__ enc,   // [B][ET][D]
    const float* __restrict__ mel,   // [B][DT][D]
    const int* __restrict__ elen, const int* __restrict__ olen,
    const float* __restrict__ vw,    // [D]
    float* __restrict__ ws,
    float* __restrict__ out_att,     // [B][DT][D]
    float* __restrict__ out_sc) {    // [B][DT][ET]
  const int tid = threadIdx.x;
  const int lane = tid & 63;
  const int wq = __builtin_amdgcn_readfirstlane(tid >> 6);  // uniform wave id
  const int bid = blockIdx.x;
  const int xcd = bid & 7, slot = bid >> 3;
  const int b = ((slot & 3) << 3) | xcd;   // perf heuristic only (L2 locality)
  const int tile = slot >> 2;              // 0..15
  const int t0 = tile * 64;

  float* pbuf = ws + PBUF_OFF + (size_t)b*2*PT;
  float* part = ws + PART_OFF + (size_t)b*16*D;
  float* Mb   = ws + M_OFF + b*16;
  float* Sb   = ws + S_OFF + b*16;
  const float* WT2 = ws + WT2_OFF;
  unsigned* cnt = (unsigned*)(ws + CNT_OFF) + b;

  __shared__ float s_pa[96], s_pc[96], s_sc[64];
  __shared__ float s_part[64][5];   // 4 wave partials per t, stride-5 pad

  const float vdr = vw[tid];        // v[d=tid], readlane'd in the d-loop
  const int L = elen[b];
  const int OL = olen[b];
  const float* wbase = WT2 + (size_t)wq * 64 * 64;   // wave's 64 weight rows

  unsigned target = 0;
#pragma unroll 1
  for (int step = 0; step < DT; ++step) {
    // -------- phase 1a: u(d=tid) from part sums; stage p into LDS --------
    float usum = 0.f;   // att_out(step-1), same summation order in every block
    {
      const float* pp = part + tid;
#pragma unroll
      for (int j = 0; j < 16; ++j) usum += aload(pp + j*D);
    }
    if (tid < 96) {
      int ix = t0 + tid; if (ix > PT-1) ix = PT-1;
      s_pa[tid] = aload(pbuf + ix);
      s_pc[tid] = aload(pbuf + PT + ix);
    }
    if (tile == 0 && step > 0) {
      float dmp = (step-1 < OL) ? 1.f : 0.f;
      out_att[((size_t)b*DT + step-1)*D + tid] = usum * dmp;
    }
    const float dm = (step < OL) ? 1.f : 0.f;
    const float ud = fmaf(mel[((size_t)b*DT + step)*D + tid], dm, usum); // u[d=tid]
    __syncthreads();

    // -------- phase 1b: conv + tanh + v-dot; lane = t, d = uniform loop --------
    // shifted windows: shA[k][lane] = p[t0+lane+k] ; 62 VGPRs, loaded once
    float shA[31], shC[31];
#pragma unroll
    for (int k = 0; k < 31; ++k) { shA[k] = s_pa[lane + k]; shC[k] = s_pc[lane + k]; }

    float e_acc = 0.f;
#pragma unroll 1
    for (int i = 0; i < 64; ++i) {
      const float* wrow = wbase + i * 64;            // uniform -> s_load into SGPRs
      float u_d = read_lane_f(ud, i);                // wave w's lane i holds u[w*64+i]
      float v_d = read_lane_f(vdr, i);
      float s0 = u_d, s1 = 0.f, s2 = 0.f, s3 = 0.f;  // 4 chains hide FMA latency
#pragma unroll
      for (int k = 0; k < 15; ++k) {
        s0 = fmaf(wrow[2*k],      shA[2*k],   s0);
        s1 = fmaf(wrow[2*k+1],    shA[2*k+1], s1);
        s2 = fmaf(wrow[32+2*k],   shC[2*k],   s2);
        s3 = fmaf(wrow[32+2*k+1], shC[2*k+1], s3);
      }
      s0 = fmaf(wrow[30], shA[30], s0);
      s2 = fmaf(wrow[62], shC[30], s2);
      float s = (s0 + s1) + (s2 + s3);
      // tanh(s) = 1 - 2/(exp(2s)+1)
      float ex = __builtin_amdgcn_exp2f(s * (2.f*LOG2E));
      float th = fmaf(-2.f, __builtin_amdgcn_rcpf(ex + 1.f), 1.f);
      e_acc = fmaf(v_d, th, e_acc);
    }
    s_part[lane][wq] = e_acc;
    __syncthreads();

    float e = 0.f;  // energy for t = t0+lane, stays in wave-0 regs across barrier
    if (tid < 64) {
      e = (s_part[tid][0] + s_part[tid][1]) + (s_part[tid][2] + s_part[tid][3]);
      float tmax = e;
#pragma unroll
      for (int msk = 1; msk < 64; msk <<= 1) tmax = fmaxf(tmax, __shfl_xor(tmax, msk, 64));
      float te = __builtin_amdgcn_exp2f((e - tmax) * LOG2E);
#pragma unroll
      for (int msk = 1; msk < 64; msk <<= 1) te += __shfl_xor(te, msk, 64);
      if (lane == 0) { astore(Mb + tile, tmax); astore(Sb + tile, te); }
    }
    target += 16;
    batch_barrier(cnt, target, tid);

    // -------- phase 2: global softmax, state update, att partials --------
    if (tid < 64) {
      float mj = aload(Mb + (lane & 15)), sj = aload(Sb + (lane & 15));
      float g = mj;
#pragma unroll
      for (int msk = 1; msk < 16; msk <<= 1) g = fmaxf(g, __shfl_xor(g, msk, 64));
      float z = sj * __builtin_amdgcn_exp2f((mj - g) * LOG2E);
#pragma unroll
      for (int msk = 1; msk < 16; msk <<= 1) z += __shfl_xor(z, msk, 64);
      float sc = __builtin_amdgcn_exp2f((e - g) * LOG2E) / z;
      int t = t0 + lane;
      if (t >= L) sc = 0.f;          // pad mask AFTER softmax (reference order)
      s_sc[lane] = sc;
      astore(pbuf + PAD + t, sc);                       // prev score
      float c = aload(pbuf + PT + PAD + t);             // cumulative (sole owner)
      astore(pbuf + PT + PAD + t, c + sc);
      out_sc[((size_t)b*DT + step)*ET + t] = sc;
    }
    __syncthreads();

    if (t0 < L) {   // tiles fully beyond elen keep part==0 (set by k_init)
      const float* eb = enc + ((size_t)b*ET + t0)*D + tid;
      float a0 = 0.f, a1 = 0.f, a2 = 0.f, a3 = 0.f;
      for (int r = 0; r < 64; r += 4) {
        a0 = fmaf(s_sc[r],   eb[(size_t)r*D],     a0);
        a1 = fmaf(s_sc[r+1], eb[(size_t)(r+1)*D], a1);
        a2 = fmaf(s_sc[r+2], eb[(size_t)(r+2)*D], a2);
        a3 = fmaf(s_sc[r+3], eb[(size_t)(r+3)*D], a3);
      }
      astore(part + tile*D + tid, (a0 + a1) + (a2 + a3));
    }
    target += 16;
    batch_barrier(cnt, target, tid);
  }

  // epilogue: out_att for the final step
  if (tile == 0) {
    float usum = 0.f;
    const float* pp = part + tid;
#pragma unroll
    for (int j = 0; j < 16; ++j) usum += aload(pp + j*D);
    float dmp = (DT-1 < OL) ? 1.f : 0.f;
    out_att[((size_t)b*DT + DT-1)*D + tid] = usum * dmp;
  }
}

extern "C" void kernel_launch(void* const* d_in, const int* in_sizes, int n_in,
                              void* d_out, int out_size, void* d_ws, size_t ws_size,
                              hipStream_t stream) {
  const float* enc = (const float*)d_in[0];
  const float* mel = (const float*)d_in[1];
  const int* elen  = (const int*)d_in[2];
  const int* olen  = (const int*)d_in[3];
  const float* vw  = (const float*)d_in[4];   // [1, D]
  const float* W   = (const float*)d_in[5];   // [D, 2, KW]

  float* out_att = (float*)d_out;                 // [B, DT, D]
  float* out_sc  = out_att + (size_t)B*DT*D;      // [B, DT, ET]
  float* ws = (float*)d_ws;

  k_init<<<128, 256, 0, stream>>>(W, ws);
  k_decoder<<<512, 256, 0, stream>>>(enc, mel, elen, olen, vw, ws, out_att, out_sc);
}

// Round 8
// 55226.343 us; speedup vs baseline: 1.4918x; 1.4918x over previous
//
#include <hip/hip_runtime.h>
#include <cstdint>

constexpr int B = 32, ET = 1024, DT = 1024, D = 256, PAD = 15, PT = ET + 2*PAD;
constexpr float LOG2E = 1.4426950408889634f;

typedef __attribute__((ext_vector_type(4))) float f32x4;

// ws float layout
constexpr size_t PBUF_OFF = 0;                           // [B][2][PT] prev,cum (halo-padded)
constexpr size_t PART_OFF = PBUF_OFF + (size_t)B*2*PT;   // [B][16][D] att_out partials
constexpr size_t M_OFF    = PART_OFF + (size_t)B*16*D;   // [B][16] tile max
constexpr size_t S_OFF    = M_OFF + (size_t)B*16;        // [B][16] tile exp-sum
constexpr size_t WT2_OFF  = S_OFF + (size_t)B*16;        // [D][64] padded weights: [d][c*32+k]
constexpr size_t CNT_OFF  = WT2_OFF + (size_t)D*64;      // [B] uint barrier counters

__global__ __launch_bounds__(256) void k_init(const float* __restrict__ W,
                                              float* __restrict__ ws) {
  int i0 = blockIdx.x*256 + threadIdx.x;
  int stride = gridDim.x*256;
  for (int i = i0; i < B*2*PT; i += stride) ws[PBUF_OFF + i] = 0.f;
  for (int i = i0; i < B*16*D; i += stride) ws[PART_OFF + i] = 0.f;
  for (int i = i0; i < D*64; i += stride) {       // WT2[d][c*32+k] = W[d][c*31+k], pad k=31 -> 0
    int d = i >> 6, r = i & 63;
    int c = r >> 5, k = r & 31;
    ws[WT2_OFF + i] = (k < 31) ? W[d*62 + c*31 + k] : 0.f;
  }
  if (i0 < B) ((unsigned*)(ws + CNT_OFF))[i0] = 0u;
}

// relaxed agent-scope accessors: coherence-point loads/stores, no cache flushes
__device__ __forceinline__ float aload(const float* p) {
  return __hip_atomic_load(p, __ATOMIC_RELAXED, __HIP_MEMORY_SCOPE_AGENT);
}
__device__ __forceinline__ void astore(float* p, float v) {
  __hip_atomic_store(p, v, __ATOMIC_RELAXED, __HIP_MEMORY_SCOPE_AGENT);
}

// per-batch arrive-and-wait, 16 blocks, monotonic counter, zero fences.
__device__ __forceinline__ void batch_barrier(unsigned* cnt, unsigned target, int tid) {
  __syncthreads();
  if (tid == 0) {
    __hip_atomic_fetch_add(cnt, 1u, __ATOMIC_RELAXED, __HIP_MEMORY_SCOPE_AGENT);
    while (__hip_atomic_load(cnt, __ATOMIC_RELAXED, __HIP_MEMORY_SCOPE_AGENT) < target)
      __builtin_amdgcn_s_sleep(2);
  }
  __syncthreads();
}

__device__ __forceinline__ float read_lane_f(float v, int i) {
  return __int_as_float(__builtin_amdgcn_readlane(__float_as_int(v), i));
}

// 8x s_load_dwordx4 (32 floats) + waitcnt in ONE asm: values land in SGPRs,
// no hazard window, no alias analysis, scalar pipe only.
#define SLOAD32(p, r0,r1,r2,r3,r4,r5,r6,r7)                                    \
  asm volatile("s_load_dwordx4 %0, %8, 0\n\t"                                  \
               "s_load_dwordx4 %1, %8, 16\n\t"                                 \
               "s_load_dwordx4 %2, %8, 32\n\t"                                 \
               "s_load_dwordx4 %3, %8, 48\n\t"                                 \
               "s_load_dwordx4 %4, %8, 64\n\t"                                 \
               "s_load_dwordx4 %5, %8, 80\n\t"                                 \
               "s_load_dwordx4 %6, %8, 96\n\t"                                 \
               "s_load_dwordx4 %7, %8, 112\n\t"                                \
               "s_waitcnt lgkmcnt(0)"                                          \
               : "=s"(r0), "=s"(r1), "=s"(r2), "=s"(r3),                       \
                 "=s"(r4), "=s"(r5), "=s"(r6), "=s"(r7)                        \
               : "s"(p))

#define WSEL(q0,q1,q2,q3,q4,q5,q6,q7,j)                                        \
  ((j) < 16 ? ((j) < 8 ? ((j) < 4 ? q0[(j)&3] : q1[(j)&3])                     \
                       : ((j) < 12 ? q2[(j)&3] : q3[(j)&3]))                   \
            : ((j) < 24 ? ((j) < 20 ? q4[(j)&3] : q5[(j)&3])                   \
                        : ((j) < 28 ? q6[(j)&3] : q7[(j)&3])))
#define WA(j) WSEL(a0,a1,a2,a3,a4,a5,a6,a7,(j))
#define WC(j) WSEL(c0,c1,c2,c3,c4,c5,c6,c7,(j))

__global__ __attribute__((amdgpu_flat_work_group_size(256, 256), amdgpu_waves_per_eu(2, 2)))
void k_decoder(
    const float* __restrict__ enc,   // [B][ET][D]
    const float* __restrict__ mel,   // [B][DT][D]
    const int* __restrict__ elen, const int* __restrict__ olen,
    const float* __restrict__ vw,    // [D]
    float* __restrict__ ws,
    float* __restrict__ out_att,     // [B][DT][D]
    float* __restrict__ out_sc) {    // [B][DT][ET]
  const int tid = threadIdx.x;
  const int lane = tid & 63;
  const int wq = __builtin_amdgcn_readfirstlane(tid >> 6);  // uniform wave id
  const int bid = blockIdx.x;
  const int xcd = bid & 7, slot = bid >> 3;
  const int b = ((slot & 3) << 3) | xcd;   // perf heuristic only (L2 locality)
  const int tile = slot >> 2;              // 0..15
  const int t0 = tile * 64;

  float* pbuf = ws + PBUF_OFF + (size_t)b*2*PT;
  float* part = ws + PART_OFF + (size_t)b*16*D;
  float* Mb   = ws + M_OFF + b*16;
  float* Sb   = ws + S_OFF + b*16;
  const float* WT2 = ws + WT2_OFF;
  unsigned* cnt = (unsigned*)(ws + CNT_OFF) + b;

  __shared__ float s_pa[96], s_pc[96], s_sc[64];
  __shared__ float s_part[64][5];   // 4 wave partials per t, stride-5 pad

  const float vdr = vw[tid];        // v[d=tid], readlane'd in the d-loop
  const int L = elen[b];
  const int OL = olen[b];
  const float* wbase = WT2 + (size_t)wq * 64 * 64;   // wave's 64 weight rows

  unsigned target = 0;
#pragma unroll 1
  for (int step = 0; step < DT; ++step) {
    // -------- phase 1a: u(d=tid) from part sums; stage p into LDS --------
    float usum = 0.f;   // att_out(step-1), same summation order in every block
    {
      const float* pp = part + tid;
#pragma unroll
      for (int j = 0; j < 16; ++j) usum += aload(pp + j*D);
    }
    if (tid < 96) {
      int ix = t0 + tid; if (ix > PT-1) ix = PT-1;
      s_pa[tid] = aload(pbuf + ix);
      s_pc[tid] = aload(pbuf + PT + ix);
    }
    if (tile == 0 && step > 0) {
      float dmp = (step-1 < OL) ? 1.f : 0.f;
      out_att[((size_t)b*DT + step-1)*D + tid] = usum * dmp;
    }
    const float dm = (step < OL) ? 1.f : 0.f;
    const float ud = fmaf(mel[((size_t)b*DT + step)*D + tid], dm, usum); // u[d=tid]
    __syncthreads();

    // -------- phase 1b: conv + tanh + v-dot; lane = t, d = uniform loop --------
    float shA[31], shC[31];   // shifted windows, ~62 VGPRs, loaded once per step
#pragma unroll
    for (int k = 0; k < 31; ++k) { shA[k] = s_pa[lane + k]; shC[k] = s_pc[lane + k]; }

    float e_acc = 0.f;
#pragma unroll 1
    for (int i = 0; i < 64; ++i) {
      const float* wrow = wbase + i * 64;   // uniform
      f32x4 a0,a1,a2,a3,a4,a5,a6,a7, c0,c1,c2,c3,c4,c5,c6,c7;
      SLOAD32(wrow,      a0,a1,a2,a3,a4,a5,a6,a7);   // A-plane w[0..31]
      SLOAD32(wrow + 32, c0,c1,c2,c3,c4,c5,c6,c7);   // C-plane w[32..63]
      float u_d = read_lane_f(ud, i);                // wave's lane i holds u[wq*64+i]
      float v_d = read_lane_f(vdr, i);
      float s0 = u_d, s1 = 0.f, s2 = 0.f, s3 = 0.f;  // 4 chains hide FMA latency
#pragma unroll
      for (int k = 0; k < 15; ++k) {
        s0 = fmaf(WA(2*k),   shA[2*k],   s0);
        s1 = fmaf(WA(2*k+1), shA[2*k+1], s1);
        s2 = fmaf(WC(2*k),   shC[2*k],   s2);
        s3 = fmaf(WC(2*k+1), shC[2*k+1], s3);
      }
      s0 = fmaf(WA(30), shA[30], s0);
      s2 = fmaf(WC(30), shC[30], s2);
      float s = (s0 + s1) + (s2 + s3);
      // tanh(s) = 1 - 2/(exp(2s)+1)
      float ex = __builtin_amdgcn_exp2f(s * (2.f*LOG2E));
      float th = fmaf(-2.f, __builtin_amdgcn_rcpf(ex + 1.f), 1.f);
      e_acc = fmaf(v_d, th, e_acc);
    }
    s_part[lane][wq] = e_acc;
    __syncthreads();

    float e = 0.f;  // energy for t = t0+lane, stays in wave-0 regs across barrier
    if (tid < 64) {
      e = (s_part[tid][0] + s_part[tid][1]) + (s_part[tid][2] + s_part[tid][3]);
      float tmax = e;
#pragma unroll
      for (int msk = 1; msk < 64; msk <<= 1) tmax = fmaxf(tmax, __shfl_xor(tmax, msk, 64));
      float te = __builtin_amdgcn_exp2f((e - tmax) * LOG2E);
#pragma unroll
      for (int msk = 1; msk < 64; msk <<= 1) te += __shfl_xor(te, msk, 64);
      if (lane == 0) { astore(Mb + tile, tmax); astore(Sb + tile, te); }
    }
    target += 16;
    batch_barrier(cnt, target, tid);

    // -------- phase 2: global softmax, state update, att partials --------
    if (tid < 64) {
      float mj = aload(Mb + (lane & 15)), sj = aload(Sb + (lane & 15));
      float g = mj;
#pragma unroll
      for (int msk = 1; msk < 16; msk <<= 1) g = fmaxf(g, __shfl_xor(g, msk, 64));
      float z = sj * __builtin_amdgcn_exp2f((mj - g) * LOG2E);
#pragma unroll
      for (int msk = 1; msk < 16; msk <<= 1) z += __shfl_xor(z, msk, 64);
      float sc = __builtin_amdgcn_exp2f((e - g) * LOG2E) / z;
      int t = t0 + lane;
      if (t >= L) sc = 0.f;          // pad mask AFTER softmax (reference order)
      s_sc[lane] = sc;
      astore(pbuf + PAD + t, sc);                       // prev score
      float c = aload(pbuf + PT + PAD + t);             // cumulative (sole owner)
      astore(pbuf + PT + PAD + t, c + sc);
      out_sc[((size_t)b*DT + step)*ET + t] = sc;
    }
    __syncthreads();

    if (t0 < L) {   // tiles fully beyond elen keep part==0 (set by k_init)
      const float* eb = enc + ((size_t)b*ET + t0)*D + tid;
      float a0 = 0.f, a1 = 0.f, a2 = 0.f, a3 = 0.f;
      for (int r = 0; r < 64; r += 4) {
        a0 = fmaf(s_sc[r],   eb[(size_t)r*D],     a0);
        a1 = fmaf(s_sc[r+1], eb[(size_t)(r+1)*D], a1);
        a2 = fmaf(s_sc[r+2], eb[(size_t)(r+2)*D], a2);
        a3 = fmaf(s_sc[r+3], eb[(size_t)(r+3)*D], a3);
      }
      astore(part + tile*D + tid, (a0 + a1) + (a2 + a3));
    }
    target += 16;
    batch_barrier(cnt, target, tid);
  }

  // epilogue: out_att for the final step
  if (tile == 0) {
    float usum = 0.f;
    const float* pp = part + tid;
#pragma unroll
    for (int j = 0; j < 16; ++j) usum += aload(pp + j*D);
    float dmp = (DT-1 < OL) ? 1.f : 0.f;
    out_att[((size_t)b*DT + DT-1)*D + tid] = usum * dmp;
  }
}

extern "C" void kernel_launch(void* const* d_in, const int* in_sizes, int n_in,
                              void* d_out, int out_size, void* d_ws, size_t ws_size,
                              hipStream_t stream) {
  const float* enc = (const float*)d_in[0];
  const float* mel = (const float*)d_in[1];
  const int* elen  = (const int*)d_in[2];
  const int* olen  = (const int*)d_in[3];
  const float* vw  = (const float*)d_in[4];   // [1, D]
  const float* W   = (const float*)d_in[5];   // [D, 2, KW]

  float* out_att = (float*)d_out;                 // [B, DT, D]
  float* out_sc  = out_att + (size_t)B*DT*D;      // [B, DT, ET]
  float* ws = (float*)d_ws;

  k_init<<<128, 256, 0, stream>>>(W, ws);
  k_decoder<<<512, 256, 0, stream>>>(enc, mel, elen, olen, vw, ws, out_att, out_sc);
}